// Round 5
// baseline (850.736 us; speedup 1.0000x reference)
//
#include <hip/hip_runtime.h>
#include <math.h>

#define NB 8
#define NH 768
#define NW 768
#define NHW (NH*NW)
#define NCEN 100
#define NPIX (NB*NHW)
#define RAD 10
#define KS 21

#define SCAN_BLKS (NPIX / 4096)   // 1152
#define BLKS_PER_B (NHW / 4096)   // 144
#define LIST_CAP 4096             // >= provable max mask px per batch (100*36=3600)
#define QBLK_PER_B (NHW / 1024)   // 576 (1024 px per block, no batch straddle)

// ws layout (ints):
#define HDR_HAS 0        // [0,8): has_inst per batch
#define HDR_SC 8         // [8,16): cmask scale bits per batch (float as uint)
#define HDR_CNT 16       // [16,24): mask-px count per batch
#define HDR_BLOCKMASK 64 // [64, 64+SCAN_BLKS*4): per-block present masks
#define HDR_LIST 8192    // [8192, 8192+NB*LIST_CAP): packed mask px (i<<16|j)

typedef float f4 __attribute__((ext_vector_type(4)));

// Separable blur weight of mask px q on output px p (one axis), incl. reflect
// images (pad=10, 'reflect' excludes edge: image exists only for 1<=q<=10 /
// 757<=q<=766). All contributing cases satisfy |p-q|<=10.
__device__ __forceinline__ float wfun(int p, int q, const float* __restrict__ g) {
    int d = p - q;
    float w = 0.f;
    if (d >= -RAD && d <= RAD) w = g[d + RAD];
    int a = p + q;
    if (q > 0 && a <= RAD) w += g[a + RAD];                 // left image t=-q
    if (q < NH - 1 && a >= 2 * (NH - 1) - RAD) w += g[a - 2 * (NH - 1) + RAD]; // right image
    return w;
}

__device__ __forceinline__ void gauss_tbl(float* g) {   // thread 0 only
    float v[KS];
    float sum = 0.f;
    for (int k = 0; k < KS; k++) {
        float x = (float)(k - RAD) * 0.5f;   // x/SIGMA, SIGMA=2
        v[k] = expf(-0.5f * x * x);
        sum += v[k];
    }
    for (int k = 0; k < KS; k++) g[k] = v[k] / sum;
}

// instances -> per-block present bitmask (plain stores, no init required).
__global__ void k_scan(const int4* __restrict__ inst4, int* __restrict__ hdr) {
    __shared__ unsigned sm[4];
    int t = threadIdx.x;
    if (t < 4) sm[t] = 0;
    __syncthreads();
    unsigned m0 = 0, m1 = 0, m2 = 0, m3 = 0;
    size_t base = (size_t)blockIdx.x * 1024 + t;   // int4 units
#pragma unroll
    for (int q = 0; q < 4; q++) {
        int4 v = inst4[base + (size_t)q * 256];
        int a[4] = {v.x, v.y, v.z, v.w};
#pragma unroll
        for (int e = 0; e < 4; e++) {
            int iv = a[e];
            if (iv > 0) {
                unsigned bit = 1u << (iv & 31);
                int w = iv >> 5;
                if (w == 0) m0 |= bit; else if (w == 1) m1 |= bit;
                else if (w == 2) m2 |= bit; else m3 |= bit;
            }
        }
    }
#pragma unroll
    for (int off = 32; off >= 1; off >>= 1) {
        m0 |= __shfl_xor(m0, off);
        m1 |= __shfl_xor(m1, off);
        m2 |= __shfl_xor(m2, off);
        m3 |= __shfl_xor(m3, off);
    }
    if ((t & 63) == 0) {
        if (m0) atomicOr(&sm[0], m0);
        if (m1) atomicOr(&sm[1], m1);
        if (m2) atomicOr(&sm[2], m2);
        if (m3) atomicOr(&sm[3], m3);
    }
    __syncthreads();
    if (t < 4) ((unsigned*)&hdr[HDR_BLOCKMASK])[blockIdx.x * 4 + t] = sm[t];
}

// One block per batch: present-reduce, gt_centers, has_inst, sparse mask-px
// find (7x7 windows around centers), exact bmax over candidate pixels, scale.
__global__ __launch_bounds__(256) void k_prep(const int* __restrict__ inst,
                                              const float* __restrict__ centers,
                                              int* __restrict__ hdr,
                                              float* __restrict__ gt) {
    __shared__ unsigned sm[4];
    __shared__ float s_g[KS];
    __shared__ int s_list[LIST_CAP];
    __shared__ int s_cnt;
    __shared__ unsigned s_bmax;
    int b = blockIdx.x, t = threadIdx.x;
    if (t < 4) sm[t] = 0;
    if (t == 0) { s_cnt = 0; s_bmax = 0; gauss_tbl(s_g); }
    __syncthreads();

    const unsigned* bm = (const unsigned*)&hdr[HDR_BLOCKMASK];
    if (t < BLKS_PER_B) {
        const unsigned* p = &bm[(b * BLKS_PER_B + t) * 4];
        unsigned w0 = p[0], w1 = p[1], w2 = p[2], w3 = p[3];
        if (w0) atomicOr(&sm[0], w0);
        if (w1) atomicOr(&sm[1], w1);
        if (w2) atomicOr(&sm[2], w2);
        if (w3) atomicOr(&sm[3], w3);
    }
    __syncthreads();
    unsigned any = (sm[0] & 0xFFFFFFFEu) | sm[1] | sm[2] | sm[3];
    int has = any ? 1 : 0;

    if (t < NCEN) {   // gt_centers
        int k = t;
        float vx = 0.f, vy = 0.f;
        if (k >= 1 && ((sm[k >> 5] >> (k & 31)) & 1u)) {
            vx = centers[(b * NCEN + (k - 1)) * 2 + 1];
            vy = centers[(b * NCEN + (k - 1)) * 2 + 0];
        }
        gt[(b * NCEN + k) * 2 + 0] = vx;
        gt[(b * NCEN + k) * 2 + 1] = vy;
    }

    // mask-px find: near px of id k+1 lie in 7x7 around (cx rows, cy cols)
    const int* instb = inst + (size_t)b * NHW;
    if (t < NCEN && has) {
        int id = t + 1;
        float cy = centers[(b * NCEN + t) * 2 + 0];
        float cx = centers[(b * NCEN + t) * 2 + 1];
        int ci = (int)floorf(cx), cj = (int)floorf(cy);
        for (int di = -3; di <= 3; di++) {
            int i = ci + di;
            if (i < 0 || i >= NH) continue;
            if (!(fabsf(cx - (float)i) < 3.f)) continue;
            for (int dj = -3; dj <= 3; dj++) {
                int j = cj + dj;
                if (j < 0 || j >= NW) continue;
                if (!(fabsf(cy - (float)j) < 3.f)) continue;
                if (instb[i * NW + j] == id) {
                    int slot = atomicAdd(&s_cnt, 1);
                    if (slot < LIST_CAP) s_list[slot] = (i << 16) | j;
                }
            }
        }
    }
    __syncthreads();
    int M = s_cnt < LIST_CAP ? s_cnt : LIST_CAP;

    // exact bmax: evaluate blur at all px within 10 of a mask px
    float lmax = 0.f;
    for (int c = t; c < M * (KS * KS); c += 256) {
        int m = c / (KS * KS), r = c - m * (KS * KS);
        int e = s_list[m];
        int pi = (e >> 16) + r / KS - RAD;
        int pj = (e & 0xFFFF) + (r - (r / KS) * KS) - RAD;
        if (pi < 0 || pi >= NH || pj < 0 || pj >= NW) continue;
        float acc = 0.f;
        for (int m2 = 0; m2 < M; m2++) {
            int e2 = s_list[m2];
            float wi = wfun(pi, e2 >> 16, s_g);
            if (wi == 0.f) continue;
            acc += wi * wfun(pj, e2 & 0xFFFF, s_g);
        }
        lmax = fmaxf(lmax, acc);
    }
    atomicMax(&s_bmax, __float_as_uint(lmax));   // lmax >= 0
    __syncthreads();

    int* gl = &hdr[HDR_LIST + b * LIST_CAP];
    for (int e2 = t; e2 < M; e2 += 256) gl[e2] = s_list[e2];
    if (t == 0) {
        float bmx = __uint_as_float(s_bmax);
        float sc = (has && M > 0) ? 1.f / fmaxf(bmx, 1e-12f) : 0.f;
        hdr[HDR_HAS + b] = has;
        hdr[HDR_SC + b] = (int)__float_as_uint(sc);
        hdr[HDR_CNT + b] = M;
    }
}

// Flat single pass: one quad (4 px) per thread; all 13 channels incl.
// normalized cmask computed from the sparse mask list. No tiling, no halo.
__global__ __launch_bounds__(256) void k_fused(const int* __restrict__ inst,
                                               const float* __restrict__ centers,
                                               const int* __restrict__ hdr,
                                               float* __restrict__ out) {
    __shared__ float s_cen[2 * NCEN];
    __shared__ float s_g[KS];
    __shared__ int s_list[LIST_CAP];
    int t = threadIdx.x;
    int b = blockIdx.x / QBLK_PER_B;
    int qblk = blockIdx.x - b * QBLK_PER_B;

    int has = hdr[HDR_HAS + b];
    int M = hdr[HDR_CNT + b];
    float sc = __uint_as_float((unsigned)hdr[HDR_SC + b]);
    for (int k = t; k < 2 * NCEN; k += 256) s_cen[k] = centers[b * 2 * NCEN + k];
    const int* gl = &hdr[HDR_LIST + b * LIST_CAP];
    for (int e = t; e < M; e += 256) s_list[e] = gl[e];
    if (t == 0) gauss_tbl(s_g);
    __syncthreads();

    int quad = qblk * 256 + t;          // quad index within batch
    int p0 = quad * 4;
    int gi = p0 / NW;                   // 192 quads/row -> no row straddle
    int gj0 = p0 - gi * NW;
    const int* instb = inst + (size_t)b * NHW;
    float* outb = out + (size_t)b * 13 * NHW;

    int4 ivv = *(const int4*)&instb[p0];
    int ia[4] = {ivv.x, ivv.y, ivv.z, ivv.w};
    f4 vR, vTh, vS, vC, vIg;
#pragma unroll
    for (int e = 0; e < 4; e++) {
        int iv = ia[e];
        bool valid = iv > 0;
        int idx = iv - 1;
        idx = idx < 0 ? 0 : idx;
        float cy = s_cen[2 * idx];
        float cx = s_cen[2 * idx + 1];
        float gcx = valid ? cx : -10000.f;
        float gcy = valid ? cy : -10000.f;
        float X = gcx - (float)gi;
        float Y = gcy - (float)(gj0 + e);
        bool near = (fabsf(X) < 3.f) && (fabsf(Y) < 3.f);
        vIg[e] = (has != 0) ? (near ? 0.f : 1.f) : 1.f;
        float m = valid ? 1.f : 0.f;
        float R2 = X * X + Y * Y;
        vR[e] = sqrtf(R2) * m;
        float rinv = R2 > 0.f ? rsqrtf(R2) : 0.f;
        vS[e] = valid ? Y * rinv : 0.f;                   // sin(atan2) masked
        vC[e] = valid ? (R2 > 0.f ? X * rinv : 1.f) : 0.f;
        float th = atan2f(Y, X);
        vTh[e] = (has != 0) ? th : 0.f;
    }

    // sparse blur + normalize (usually 0-2 entries pass the wi test)
    f4 blur = {0.f, 0.f, 0.f, 0.f};
    for (int m = 0; m < M; m++) {
        int e2 = s_list[m];
        float wi = wfun(gi, e2 >> 16, s_g);
        if (wi == 0.f) continue;
        int qj = e2 & 0xFFFF;
#pragma unroll
        for (int e = 0; e < 4; e++) blur[e] += wi * wfun(gj0 + e, qj, s_g);
    }
    f4 vCm = blur * sc;

    __builtin_nontemporal_store(vR,  (f4*)&outb[(size_t)0 * NHW + p0]);
    __builtin_nontemporal_store(vTh, (f4*)&outb[(size_t)1 * NHW + p0]);
    __builtin_nontemporal_store(vS,  (f4*)&outb[(size_t)2 * NHW + p0]);
    __builtin_nontemporal_store(vC,  (f4*)&outb[(size_t)3 * NHW + p0]);
    __builtin_nontemporal_store(vIg, (f4*)&outb[(size_t)4 * NHW + p0]);
    __builtin_nontemporal_store(vCm, (f4*)&outb[(size_t)5 * NHW + p0]);
    f4 z = {0.f, 0.f, 0.f, 0.f};
#pragma unroll
    for (int ch = 6; ch < 13; ++ch)
        __builtin_nontemporal_store(z, (f4*)&outb[(size_t)ch * NHW + p0]);
}

extern "C" void kernel_launch(void* const* d_in, const int* in_sizes, int n_in,
                              void* d_out, int out_size, void* d_ws, size_t ws_size,
                              hipStream_t stream) {
    const int* inst = (const int*)d_in[0];
    const float* centers = (const float*)d_in[1];
    float* out = (float*)d_out;
    int* hdr = (int*)d_ws;
    float* gt = out + (size_t)NB * 13 * NHW;

    k_scan<<<SCAN_BLKS, 256, 0, stream>>>((const int4*)inst, hdr);
    k_prep<<<NB, 256, 0, stream>>>(inst, centers, hdr, gt);
    k_fused<<<NB * QBLK_PER_B, 256, 0, stream>>>(inst, centers, hdr, out);
}

// Round 6
// 293.977 us; speedup vs baseline: 2.8939x; 2.8939x over previous
//
#include <hip/hip_runtime.h>
#include <math.h>

#define NB 8
#define NH 768
#define NW 768
#define NHW (NH*NW)
#define NCEN 100
#define NPIX (NB*NHW)
#define RAD 10
#define KS 21

#define SCAN_BLKS (NPIX / 4096)   // 1152
#define BLKS_PER_B (NHW / 4096)   // 144
#define LIST_CAP 4096             // >= provable max mask px per batch (100*36=3600)
#define QBLK_PER_B (NHW / 1024)   // 576 (1024 px per block; always spans exactly 2 rows)
#define CAND_BLKS 96              // bmax blocks per batch
#define FCAP 1024                 // filtered-list cap (block spans 2 rows; real M ~50)

// ws layout (ints):
#define HDR_HAS 0        // [0,8): has_inst per batch
#define HDR_CNT 8        // [8,16): mask-px count per batch
#define HDR_BMAX 16      // [16,24): bmax bits (uint, nonneg float) per batch
#define HDR_BLOCKMASK 64 // [64, 64+SCAN_BLKS*4): per-block present masks
#define HDR_LIST 8192    // [8192, 8192+NB*LIST_CAP): packed mask px (i<<16|j)

typedef float f4 __attribute__((ext_vector_type(4)));

// Separable blur weight of mask px q on output px p (one axis), incl. reflect
// images ('reflect' excludes edge: left image exists for q>=1, right for q<=766).
__device__ __forceinline__ float wfun(int p, int q, const float* __restrict__ g) {
    int d = p - q;
    float w = 0.f;
    if (d >= -RAD && d <= RAD) w = g[d + RAD];
    int a = p + q;
    if (q > 0 && a <= RAD) w += g[a + RAD];                               // left image
    if (q < NH - 1 && a >= 2 * (NH - 1) - RAD) w += g[a - 2 * (NH - 1) + RAD]; // right image
    return w;
}

__device__ __forceinline__ void gauss_tbl(float* g) {   // thread 0 only
    float v[KS];
    float sum = 0.f;
    for (int k = 0; k < KS; k++) {
        float x = (float)(k - RAD) * 0.5f;   // x/SIGMA, SIGMA=2
        v[k] = expf(-0.5f * x * x);
        sum += v[k];
    }
    for (int k = 0; k < KS; k++) g[k] = v[k] / sum;
}

// instances -> per-block present bitmask (plain stores, no init required).
__global__ void k_scan(const int4* __restrict__ inst4, int* __restrict__ hdr) {
    __shared__ unsigned sm[4];
    int t = threadIdx.x;
    if (t < 4) sm[t] = 0;
    __syncthreads();
    unsigned m0 = 0, m1 = 0, m2 = 0, m3 = 0;
    size_t base = (size_t)blockIdx.x * 1024 + t;   // int4 units
#pragma unroll
    for (int q = 0; q < 4; q++) {
        int4 v = inst4[base + (size_t)q * 256];
        int a[4] = {v.x, v.y, v.z, v.w};
#pragma unroll
        for (int e = 0; e < 4; e++) {
            int iv = a[e];
            if (iv > 0) {
                unsigned bit = 1u << (iv & 31);
                int w = iv >> 5;
                if (w == 0) m0 |= bit; else if (w == 1) m1 |= bit;
                else if (w == 2) m2 |= bit; else m3 |= bit;
            }
        }
    }
#pragma unroll
    for (int off = 32; off >= 1; off >>= 1) {
        m0 |= __shfl_xor(m0, off);
        m1 |= __shfl_xor(m1, off);
        m2 |= __shfl_xor(m2, off);
        m3 |= __shfl_xor(m3, off);
    }
    if ((t & 63) == 0) {
        if (m0) atomicOr(&sm[0], m0);
        if (m1) atomicOr(&sm[1], m1);
        if (m2) atomicOr(&sm[2], m2);
        if (m3) atomicOr(&sm[3], m3);
    }
    __syncthreads();
    if (t < 4) ((unsigned*)&hdr[HDR_BLOCKMASK])[blockIdx.x * 4 + t] = sm[t];
}

// One block per batch: present-reduce, gt_centers, has_inst, sparse mask-px
// find (strided over 100x49 center-window pairs). No bmax here (k_bmax does it).
__global__ __launch_bounds__(256) void k_prep(const int* __restrict__ inst,
                                              const float* __restrict__ centers,
                                              int* __restrict__ hdr,
                                              float* __restrict__ gt) {
    __shared__ unsigned sm[4];
    __shared__ float s_cen[2 * NCEN];
    __shared__ int s_list[LIST_CAP];
    __shared__ int s_cnt;
    int b = blockIdx.x, t = threadIdx.x;
    if (t < 4) sm[t] = 0;
    if (t == 0) s_cnt = 0;
    for (int k = t; k < 2 * NCEN; k += 256) s_cen[k] = centers[b * 2 * NCEN + k];
    __syncthreads();

    const unsigned* bm = (const unsigned*)&hdr[HDR_BLOCKMASK];
    if (t < BLKS_PER_B) {
        const unsigned* p = &bm[(b * BLKS_PER_B + t) * 4];
        unsigned w0 = p[0], w1 = p[1], w2 = p[2], w3 = p[3];
        if (w0) atomicOr(&sm[0], w0);
        if (w1) atomicOr(&sm[1], w1);
        if (w2) atomicOr(&sm[2], w2);
        if (w3) atomicOr(&sm[3], w3);
    }
    __syncthreads();
    unsigned any = (sm[0] & 0xFFFFFFFEu) | sm[1] | sm[2] | sm[3];
    int has = any ? 1 : 0;

    if (t < NCEN) {   // gt_centers
        int k = t;
        float vx = 0.f, vy = 0.f;
        if (k >= 1 && ((sm[k >> 5] >> (k & 31)) & 1u)) {
            vx = s_cen[(k - 1) * 2 + 1];
            vy = s_cen[(k - 1) * 2 + 0];
        }
        gt[(b * NCEN + k) * 2 + 0] = vx;
        gt[(b * NCEN + k) * 2 + 1] = vy;
    }

    // mask-px find: near px of id k+1 lie in 7x7 around (cx rows, cy cols)
    const int* instb = inst + (size_t)b * NHW;
    if (has) {
        for (int c = t; c < NCEN * 49; c += 256) {
            int k = c / 49, r = c - k * 49;
            float cy = s_cen[2 * k];
            float cx = s_cen[2 * k + 1];
            int i = (int)floorf(cx) + r / 7 - 3;
            int j = (int)floorf(cy) + (r - (r / 7) * 7) - 3;
            if (i < 0 || i >= NH || j < 0 || j >= NW) continue;
            if (!(fabsf(cx - (float)i) < 3.f) || !(fabsf(cy - (float)j) < 3.f)) continue;
            if (instb[i * NW + j] == k + 1) {
                int slot = atomicAdd(&s_cnt, 1);
                if (slot < LIST_CAP) s_list[slot] = (i << 16) | j;
            }
        }
    }
    __syncthreads();
    int M = s_cnt < LIST_CAP ? s_cnt : LIST_CAP;
    int* gl = &hdr[HDR_LIST + b * LIST_CAP];
    for (int e = t; e < M; e += 256) gl[e] = s_list[e];
    if (t == 0) {
        hdr[HDR_HAS + b] = has;
        hdr[HDR_CNT + b] = M;
        hdr[HDR_BMAX + b] = 0;
    }
}

// Exact bmax, parallel: 96 blocks/batch over M*441 candidate px (blur==0 elsewhere).
__global__ __launch_bounds__(256) void k_bmax(int* __restrict__ hdr) {
    __shared__ float s_g[KS];
    __shared__ int s_list[LIST_CAP];
    __shared__ float s_red[4];
    int t = threadIdx.x;
    int b = blockIdx.x / CAND_BLKS;
    int cb = blockIdx.x - b * CAND_BLKS;
    int M = hdr[HDR_CNT + b];
    if (M == 0) return;
    if (t == 0) gauss_tbl(s_g);
    const int* gl = &hdr[HDR_LIST + b * LIST_CAP];
    for (int e = t; e < M; e += 256) s_list[e] = gl[e];
    __syncthreads();

    float lmax = 0.f;
    int total = M * (KS * KS);
    for (int c = cb * 256 + t; c < total; c += CAND_BLKS * 256) {
        int m = c / (KS * KS), r = c - m * (KS * KS);
        int e = s_list[m];
        int pi = (e >> 16) + r / KS - RAD;
        int pj = (e & 0xFFFF) + (r - (r / KS) * KS) - RAD;
        if (pi < 0 || pi >= NH || pj < 0 || pj >= NW) continue;
        float acc = 0.f;
        for (int m2 = 0; m2 < M; m2++) {
            int e2 = s_list[m2];
            float wi = wfun(pi, e2 >> 16, s_g);
            if (wi == 0.f) continue;
            acc += wi * wfun(pj, e2 & 0xFFFF, s_g);
        }
        lmax = fmaxf(lmax, acc);
    }
#pragma unroll
    for (int off = 32; off >= 1; off >>= 1) lmax = fmaxf(lmax, __shfl_down(lmax, off));
    if ((t & 63) == 0) s_red[t >> 6] = lmax;
    __syncthreads();
    if (t == 0) {
        float bmx = fmaxf(fmaxf(s_red[0], s_red[1]), fmaxf(s_red[2], s_red[3]));
        atomicMax((unsigned*)&hdr[HDR_BMAX + b], __float_as_uint(bmx));  // >= 0
    }
}

// Flat single pass: one quad (4 px) per thread; all 13 channels incl. normalized
// cmask from the row-prefiltered sparse list. Each block spans exactly 2 rows.
__global__ __launch_bounds__(256) void k_fused(const int* __restrict__ inst,
                                               const float* __restrict__ centers,
                                               const int* __restrict__ hdr,
                                               float* __restrict__ out) {
    __shared__ float s_cen[2 * NCEN];
    __shared__ float s_g[KS];
    __shared__ int s_fl[FCAP];
    __shared__ int s_fM;
    int t = threadIdx.x;
    int b = blockIdx.x / QBLK_PER_B;
    int qblk = blockIdx.x - b * QBLK_PER_B;

    int has = hdr[HDR_HAS + b];
    int M = hdr[HDR_CNT + b];
    float bmx = __uint_as_float((unsigned)hdr[HDR_BMAX + b]);
    float sc = (has && M > 0) ? 1.f / fmaxf(bmx, 1e-12f) : 0.f;
    for (int k = t; k < 2 * NCEN; k += 256) s_cen[k] = centers[b * 2 * NCEN + k];
    if (t == 0) { gauss_tbl(s_g); }
    if (t == 1) s_fM = 0;
    __syncthreads();

    // row prefilter: keep entries with nonzero row weight for either spanned row
    int p0blk = qblk * 1024;
    int r0 = p0blk / NW;
    const int* gl = &hdr[HDR_LIST + b * LIST_CAP];
    for (int m = t; m < M; m += 256) {
        int e = gl[m];
        int qi = e >> 16;
        if (wfun(r0, qi, s_g) != 0.f || wfun(r0 + 1, qi, s_g) != 0.f) {
            int slot = atomicAdd(&s_fM, 1);
            if (slot < FCAP) s_fl[slot] = e;
        }
    }
    __syncthreads();
    int FM = s_fM < FCAP ? s_fM : FCAP;

    int p0 = p0blk + t * 4;
    int gi = p0 / NW;                   // 192 quads/row -> no row straddle
    int gj0 = p0 - gi * NW;
    const int* instb = inst + (size_t)b * NHW;
    float* outb = out + (size_t)b * 13 * NHW;

    int4 ivv = *(const int4*)&instb[p0];
    int ia[4] = {ivv.x, ivv.y, ivv.z, ivv.w};
    f4 vR, vTh, vS, vC, vIg;
#pragma unroll
    for (int e = 0; e < 4; e++) {
        int iv = ia[e];
        bool valid = iv > 0;
        int idx = iv - 1;
        idx = idx < 0 ? 0 : idx;
        float cy = s_cen[2 * idx];
        float cx = s_cen[2 * idx + 1];
        float gcx = valid ? cx : -10000.f;
        float gcy = valid ? cy : -10000.f;
        float X = gcx - (float)gi;
        float Y = gcy - (float)(gj0 + e);
        bool near = (fabsf(X) < 3.f) && (fabsf(Y) < 3.f);
        vIg[e] = (has != 0) ? (near ? 0.f : 1.f) : 1.f;
        float m = valid ? 1.f : 0.f;
        float R2 = X * X + Y * Y;
        vR[e] = sqrtf(R2) * m;
        float rinv = R2 > 0.f ? rsqrtf(R2) : 0.f;
        vS[e] = valid ? Y * rinv : 0.f;                   // sin(atan2) masked
        vC[e] = valid ? (R2 > 0.f ? X * rinv : 1.f) : 0.f;
        float th = atan2f(Y, X);
        vTh[e] = (has != 0) ? th : 0.f;
    }

    // sparse blur over the filtered list (typically 0-2 entries)
    f4 blur = {0.f, 0.f, 0.f, 0.f};
    for (int m = 0; m < FM; m++) {
        int e2 = s_fl[m];
        float wi = wfun(gi, e2 >> 16, s_g);
        if (wi == 0.f) continue;
        int qj = e2 & 0xFFFF;
#pragma unroll
        for (int e = 0; e < 4; e++) blur[e] += wi * wfun(gj0 + e, qj, s_g);
    }
    f4 vCm = blur * sc;

    __builtin_nontemporal_store(vR,  (f4*)&outb[(size_t)0 * NHW + p0]);
    __builtin_nontemporal_store(vTh, (f4*)&outb[(size_t)1 * NHW + p0]);
    __builtin_nontemporal_store(vS,  (f4*)&outb[(size_t)2 * NHW + p0]);
    __builtin_nontemporal_store(vC,  (f4*)&outb[(size_t)3 * NHW + p0]);
    __builtin_nontemporal_store(vIg, (f4*)&outb[(size_t)4 * NHW + p0]);
    __builtin_nontemporal_store(vCm, (f4*)&outb[(size_t)5 * NHW + p0]);
    f4 z = {0.f, 0.f, 0.f, 0.f};
#pragma unroll
    for (int ch = 6; ch < 13; ++ch)
        __builtin_nontemporal_store(z, (f4*)&outb[(size_t)ch * NHW + p0]);
}

extern "C" void kernel_launch(void* const* d_in, const int* in_sizes, int n_in,
                              void* d_out, int out_size, void* d_ws, size_t ws_size,
                              hipStream_t stream) {
    const int* inst = (const int*)d_in[0];
    const float* centers = (const float*)d_in[1];
    float* out = (float*)d_out;
    int* hdr = (int*)d_ws;
    float* gt = out + (size_t)NB * 13 * NHW;

    k_scan<<<SCAN_BLKS, 256, 0, stream>>>((const int4*)inst, hdr);
    k_prep<<<NB, 256, 0, stream>>>(inst, centers, hdr, gt);
    k_bmax<<<NB * CAND_BLKS, 256, 0, stream>>>(hdr);
    k_fused<<<NB * QBLK_PER_B, 256, 0, stream>>>(inst, centers, hdr, out);
}

// Round 7
// 293.404 us; speedup vs baseline: 2.8995x; 1.0020x over previous
//
#include <hip/hip_runtime.h>
#include <math.h>

#define NB 8
#define NH 768
#define NW 768
#define NHW (NH*NW)
#define NCEN 100
#define NPIX (NB*NHW)
#define RAD 10
#define KS 21

#define SCAN_BLKS (NPIX / 4096)   // 1152
#define BLKS_PER_B (NHW / 4096)   // 144
#define LIST_CAP 4096             // >= provable max mask px per batch (100*36=3600)
#define QBLK_PER_B (NHW / 1024)   // 576 (1024 px per block; spans exactly rows r0,r0+1)
#define CAND_BLKS 96              // bmax blocks per batch
#define FCAP 1024                 // filtered-list cap (block spans 2 rows; real M ~50)

// ws layout (ints):
#define HDR_HAS 0        // [0,8): has_inst per batch
#define HDR_CNT 8        // [8,16): mask-px count per batch
#define HDR_BMAX 16      // [16,24): bmax bits (uint, nonneg float) per batch
#define HDR_BLOCKMASK 64 // [64, 64+SCAN_BLKS*4): per-block present masks
#define HDR_LIST 8192    // [8192, 8192+NB*LIST_CAP): packed mask px (i<<16|j)

typedef float f4 __attribute__((ext_vector_type(4)));

// Normalized 21-tap Gaussian (sigma=2), precomputed; rel err ~1e-7 vs float ref.
__device__ const float g_G[KS] = {
    7.4335e-7f, 7.9919e-6f, 6.6915e-5f, 0.00043634f, 0.00221592f,
    0.00876415f, 0.02699548f, 0.06475880f, 0.12098536f, 0.17603266f,
    0.19947114f,
    0.17603266f, 0.12098536f, 0.06475880f, 0.02699548f, 0.00876415f,
    0.00221592f, 0.00043634f, 6.6915e-5f, 7.9919e-6f, 7.4335e-7f};

// Separable blur weight of mask px q on output px p (one axis), incl. reflect
// images ('reflect' excludes edge: left image exists for q>=1, right for q<=766).
__device__ __forceinline__ float wfun(int p, int q, const float* __restrict__ g) {
    int d = p - q;
    float w = 0.f;
    if (d >= -RAD && d <= RAD) w = g[d + RAD];
    int a = p + q;
    if (q > 0 && a <= RAD) w += g[a + RAD];                               // left image
    if (q < NH - 1 && a >= 2 * (NH - 1) - RAD) w += g[a - 2 * (NH - 1) + RAD]; // right image
    return w;
}

// Fast atan2: 6-term minimax atan poly on [0,1], quadrant fixup. |err| ~1e-5 rad.
__device__ __forceinline__ float fatan2(float Y, float X) {
    float ax = fabsf(X), ay = fabsf(Y);
    float mx = fmaxf(ax, ay), mn = fminf(ax, ay);
    float a = mx > 0.f ? __fdividef(mn, mx) : 0.f;
    float ss = a * a;
    float r = fmaf(fmaf(fmaf(fmaf(fmaf(-0.01172120f, ss, 0.05265332f), ss,
                -0.11643287f), ss, 0.19354346f), ss, -0.33262347f), ss, 0.99997726f) * a;
    if (ay > ax) r = 1.57079637f - r;
    if (X < 0.f) r = 3.14159274f - r;
    return copysignf(r, Y);
}

// instances -> per-block present bitmask (plain stores, no init required).
__global__ void k_scan(const int4* __restrict__ inst4, int* __restrict__ hdr) {
    __shared__ unsigned sm[4];
    int t = threadIdx.x;
    if (t < 4) sm[t] = 0;
    __syncthreads();
    unsigned m0 = 0, m1 = 0, m2 = 0, m3 = 0;
    size_t base = (size_t)blockIdx.x * 1024 + t;   // int4 units
#pragma unroll
    for (int q = 0; q < 4; q++) {
        int4 v = inst4[base + (size_t)q * 256];
        int a[4] = {v.x, v.y, v.z, v.w};
#pragma unroll
        for (int e = 0; e < 4; e++) {
            int iv = a[e];
            if (iv > 0) {
                unsigned bit = 1u << (iv & 31);
                int w = iv >> 5;
                if (w == 0) m0 |= bit; else if (w == 1) m1 |= bit;
                else if (w == 2) m2 |= bit; else m3 |= bit;
            }
        }
    }
#pragma unroll
    for (int off = 32; off >= 1; off >>= 1) {
        m0 |= __shfl_xor(m0, off);
        m1 |= __shfl_xor(m1, off);
        m2 |= __shfl_xor(m2, off);
        m3 |= __shfl_xor(m3, off);
    }
    if ((t & 63) == 0) {
        if (m0) atomicOr(&sm[0], m0);
        if (m1) atomicOr(&sm[1], m1);
        if (m2) atomicOr(&sm[2], m2);
        if (m3) atomicOr(&sm[3], m3);
    }
    __syncthreads();
    if (t < 4) ((unsigned*)&hdr[HDR_BLOCKMASK])[blockIdx.x * 4 + t] = sm[t];
}

// One block per batch: present-reduce, gt_centers, has_inst, sparse mask-px
// find (strided over 100x49 center-window pairs). No bmax here (k_bmax does it).
__global__ __launch_bounds__(256) void k_prep(const int* __restrict__ inst,
                                              const float* __restrict__ centers,
                                              int* __restrict__ hdr,
                                              float* __restrict__ gt) {
    __shared__ unsigned sm[4];
    __shared__ float s_cen[2 * NCEN];
    __shared__ int s_list[LIST_CAP];
    __shared__ int s_cnt;
    int b = blockIdx.x, t = threadIdx.x;
    if (t < 4) sm[t] = 0;
    if (t == 0) s_cnt = 0;
    for (int k = t; k < 2 * NCEN; k += 256) s_cen[k] = centers[b * 2 * NCEN + k];
    __syncthreads();

    const unsigned* bm = (const unsigned*)&hdr[HDR_BLOCKMASK];
    if (t < BLKS_PER_B) {
        const unsigned* p = &bm[(b * BLKS_PER_B + t) * 4];
        unsigned w0 = p[0], w1 = p[1], w2 = p[2], w3 = p[3];
        if (w0) atomicOr(&sm[0], w0);
        if (w1) atomicOr(&sm[1], w1);
        if (w2) atomicOr(&sm[2], w2);
        if (w3) atomicOr(&sm[3], w3);
    }
    __syncthreads();
    unsigned any = (sm[0] & 0xFFFFFFFEu) | sm[1] | sm[2] | sm[3];
    int has = any ? 1 : 0;

    if (t < NCEN) {   // gt_centers
        int k = t;
        float vx = 0.f, vy = 0.f;
        if (k >= 1 && ((sm[k >> 5] >> (k & 31)) & 1u)) {
            vx = s_cen[(k - 1) * 2 + 1];
            vy = s_cen[(k - 1) * 2 + 0];
        }
        gt[(b * NCEN + k) * 2 + 0] = vx;
        gt[(b * NCEN + k) * 2 + 1] = vy;
    }

    // mask-px find: near px of id k+1 lie in 7x7 around (cx rows, cy cols)
    const int* instb = inst + (size_t)b * NHW;
    if (has) {
        for (int c = t; c < NCEN * 49; c += 256) {
            int k = c / 49, r = c - k * 49;
            float cy = s_cen[2 * k];
            float cx = s_cen[2 * k + 1];
            int i = (int)floorf(cx) + r / 7 - 3;
            int j = (int)floorf(cy) + (r - (r / 7) * 7) - 3;
            if (i < 0 || i >= NH || j < 0 || j >= NW) continue;
            if (!(fabsf(cx - (float)i) < 3.f) || !(fabsf(cy - (float)j) < 3.f)) continue;
            if (instb[i * NW + j] == k + 1) {
                int slot = atomicAdd(&s_cnt, 1);
                if (slot < LIST_CAP) s_list[slot] = (i << 16) | j;
            }
        }
    }
    __syncthreads();
    int M = s_cnt < LIST_CAP ? s_cnt : LIST_CAP;
    int* gl = &hdr[HDR_LIST + b * LIST_CAP];
    for (int e = t; e < M; e += 256) gl[e] = s_list[e];
    if (t == 0) {
        hdr[HDR_HAS + b] = has;
        hdr[HDR_CNT + b] = M;
        hdr[HDR_BMAX + b] = 0;
    }
}

// Exact bmax, parallel: 96 blocks/batch over M*441 candidate px (blur==0 elsewhere).
__global__ __launch_bounds__(256) void k_bmax(int* __restrict__ hdr) {
    __shared__ float s_g[KS];
    __shared__ int s_list[LIST_CAP];
    __shared__ float s_red[4];
    int t = threadIdx.x;
    int b = blockIdx.x / CAND_BLKS;
    int cb = blockIdx.x - b * CAND_BLKS;
    int M = hdr[HDR_CNT + b];
    int total = M * (KS * KS);
    if (M == 0 || cb * 256 >= total) return;   // workless block
    if (t < KS) s_g[t] = g_G[t];
    const int* gl = &hdr[HDR_LIST + b * LIST_CAP];
    for (int e = t; e < M; e += 256) s_list[e] = gl[e];
    __syncthreads();

    float lmax = 0.f;
    for (int c = cb * 256 + t; c < total; c += CAND_BLKS * 256) {
        int m = c / (KS * KS), r = c - m * (KS * KS);
        int e = s_list[m];
        int pi = (e >> 16) + r / KS - RAD;
        int pj = (e & 0xFFFF) + (r - (r / KS) * KS) - RAD;
        if (pi < 0 || pi >= NH || pj < 0 || pj >= NW) continue;
        float acc = 0.f;
        for (int m2 = 0; m2 < M; m2++) {
            int e2 = s_list[m2];
            float wi = wfun(pi, e2 >> 16, s_g);
            if (wi == 0.f) continue;
            acc += wi * wfun(pj, e2 & 0xFFFF, s_g);
        }
        lmax = fmaxf(lmax, acc);
    }
#pragma unroll
    for (int off = 32; off >= 1; off >>= 1) lmax = fmaxf(lmax, __shfl_down(lmax, off));
    if ((t & 63) == 0) s_red[t >> 6] = lmax;
    __syncthreads();
    if (t == 0) {
        float bmx = fmaxf(fmaxf(s_red[0], s_red[1]), fmaxf(s_red[2], s_red[3]));
        atomicMax((unsigned*)&hdr[HDR_BMAX + b], __float_as_uint(bmx));  // >= 0
    }
}

// Flat single pass: one quad (4 px) per thread; all 13 channels incl. normalized
// cmask from the row-prefiltered sparse list. Each block spans exactly 2 rows.
__global__ __launch_bounds__(256) void k_fused(const int* __restrict__ inst,
                                               const float* __restrict__ centers,
                                               const int* __restrict__ hdr,
                                               float* __restrict__ out) {
    __shared__ float s_cen[2 * NCEN];
    __shared__ float s_g[KS];
    __shared__ int s_fl[FCAP];
    __shared__ int s_fM;
    int t = threadIdx.x;
    int b = blockIdx.x / QBLK_PER_B;
    int qblk = blockIdx.x - b * QBLK_PER_B;

    int has = hdr[HDR_HAS + b];
    int M = hdr[HDR_CNT + b];
    float bmx = __uint_as_float((unsigned)hdr[HDR_BMAX + b]);
    float sc = (has && M > 0) ? 1.f / fmaxf(bmx, 1e-12f) : 0.f;
    for (int k = t; k < 2 * NCEN; k += 256) s_cen[k] = centers[b * 2 * NCEN + k];
    if (t < KS) s_g[t] = g_G[t];
    if (t == 255) s_fM = 0;
    __syncthreads();

    // row prefilter: keep entries with nonzero row weight for either spanned row
    int p0blk = qblk * 1024;
    int r0 = p0blk / NW;
    const int* gl = &hdr[HDR_LIST + b * LIST_CAP];
    for (int m = t; m < M; m += 256) {
        int e = gl[m];
        int qi = e >> 16;
        if (wfun(r0, qi, s_g) != 0.f || wfun(r0 + 1, qi, s_g) != 0.f) {
            int slot = atomicAdd(&s_fM, 1);
            if (slot < FCAP) s_fl[slot] = e;
        }
    }
    __syncthreads();
    int FM = s_fM < FCAP ? s_fM : FCAP;

    int p0 = p0blk + t * 4;
    int gi = p0 / NW;                   // 192 quads/row -> no row straddle
    int gj0 = p0 - gi * NW;
    const int* instb = inst + (size_t)b * NHW;
    float* outb = out + (size_t)b * 13 * NHW;

    int4 ivv = *(const int4*)&instb[p0];
    int ia[4] = {ivv.x, ivv.y, ivv.z, ivv.w};
    f4 vR, vTh, vS, vC, vIg;
#pragma unroll
    for (int e = 0; e < 4; e++) {
        int iv = ia[e];
        bool valid = iv > 0;
        int idx = iv - 1;
        idx = idx < 0 ? 0 : idx;
        float cy = s_cen[2 * idx];
        float cx = s_cen[2 * idx + 1];
        float gcx = valid ? cx : -10000.f;
        float gcy = valid ? cy : -10000.f;
        float X = gcx - (float)gi;
        float Y = gcy - (float)(gj0 + e);
        bool near = (fabsf(X) < 3.f) && (fabsf(Y) < 3.f);
        vIg[e] = (has != 0) ? (near ? 0.f : 1.f) : 1.f;
        float m = valid ? 1.f : 0.f;
        float R2 = X * X + Y * Y;
        vR[e] = sqrtf(R2) * m;
        float rinv = R2 > 0.f ? rsqrtf(R2) : 0.f;
        vS[e] = valid ? Y * rinv : 0.f;                   // sin(atan2) masked
        vC[e] = valid ? (R2 > 0.f ? X * rinv : 1.f) : 0.f;
        float th = fatan2(Y, X);
        vTh[e] = (has != 0) ? th : 0.f;
    }

    // sparse blur over the filtered list (typically 0-2 entries)
    f4 blur = {0.f, 0.f, 0.f, 0.f};
    for (int m = 0; m < FM; m++) {
        int e2 = s_fl[m];
        float wi = wfun(gi, e2 >> 16, s_g);
        if (wi == 0.f) continue;
        int qj = e2 & 0xFFFF;
#pragma unroll
        for (int e = 0; e < 4; e++) blur[e] += wi * wfun(gj0 + e, qj, s_g);
    }
    f4 vCm = blur * sc;

    __builtin_nontemporal_store(vR,  (f4*)&outb[(size_t)0 * NHW + p0]);
    __builtin_nontemporal_store(vTh, (f4*)&outb[(size_t)1 * NHW + p0]);
    __builtin_nontemporal_store(vS,  (f4*)&outb[(size_t)2 * NHW + p0]);
    __builtin_nontemporal_store(vC,  (f4*)&outb[(size_t)3 * NHW + p0]);
    __builtin_nontemporal_store(vIg, (f4*)&outb[(size_t)4 * NHW + p0]);
    __builtin_nontemporal_store(vCm, (f4*)&outb[(size_t)5 * NHW + p0]);
    f4 z = {0.f, 0.f, 0.f, 0.f};
#pragma unroll
    for (int ch = 6; ch < 13; ++ch)
        __builtin_nontemporal_store(z, (f4*)&outb[(size_t)ch * NHW + p0]);
}

extern "C" void kernel_launch(void* const* d_in, const int* in_sizes, int n_in,
                              void* d_out, int out_size, void* d_ws, size_t ws_size,
                              hipStream_t stream) {
    const int* inst = (const int*)d_in[0];
    const float* centers = (const float*)d_in[1];
    float* out = (float*)d_out;
    int* hdr = (int*)d_ws;
    float* gt = out + (size_t)NB * 13 * NHW;

    k_scan<<<SCAN_BLKS, 256, 0, stream>>>((const int4*)inst, hdr);
    k_prep<<<NB, 256, 0, stream>>>(inst, centers, hdr, gt);
    k_bmax<<<NB * CAND_BLKS, 256, 0, stream>>>(hdr);
    k_fused<<<NB * QBLK_PER_B, 256, 0, stream>>>(inst, centers, hdr, out);
}